// Round 5
// baseline (639.577 us; speedup 1.0000x reference)
//
#include <hip/hip_runtime.h>
#include <hip/hip_bf16.h>
#include <math.h>
#include <stdint.h>

#define TOK 4096
#define SEQ 2048
#define NDIM 2048
#define NH 16
#define QR 1536
#define KVR 512
#define NOPE_D 128
#define QKH 192
#define QDIM 3072
#define KVDIM 4096
#define CW 640
#define ODIM 2048

typedef __attribute__((ext_vector_type(4))) float f32x4;
typedef __attribute__((ext_vector_type(8))) __bf16 bf16x8;
typedef __attribute__((ext_vector_type(8))) unsigned short u16x8;
typedef __attribute__((ext_vector_type(4))) unsigned short u16x4;

__device__ inline unsigned short f2bf(float f) {
  union { float f; uint32_t u; } v; v.f = f;
  uint32_t r = (v.u + 0x7FFFu + ((v.u >> 16) & 1u)) >> 16;
  return (unsigned short)r;
}
__device__ inline float bf2f(unsigned short s) {
  union { uint32_t u; float f; } v; v.u = ((uint32_t)s) << 16;
  return v.f;
}

// async global->LDS, 16B per lane. LDS dest is wave-uniform base + lane*16.
__device__ inline void gload16(const void* g, void* l) {
  __builtin_amdgcn_global_load_lds(
      (const __attribute__((address_space(1))) unsigned int*)g,
      (__attribute__((address_space(3))) unsigned int*)l, 16, 0, 0);
}

__global__ __launch_bounds__(256) void cvt_kernel(const float* __restrict__ in,
                                                  unsigned short* __restrict__ out, long n) {
  long i = ((long)blockIdx.x * 256 + threadIdx.x) * 4;
  if (i >= n) return;
  f32x4 v = *(const f32x4*)(in + i);
  u16x4 o;
  #pragma unroll
  for (int j = 0; j < 4; j++) o[j] = f2bf(v[j]);
  *(u16x4*)(out + i) = o;
}

__global__ __launch_bounds__(256) void zero_kernel(unsigned short* __restrict__ out, long n) {
  long i = ((long)blockIdx.x * 256 + threadIdx.x) * 4;
  if (i >= n) return;
  u16x4 z = {0, 0, 0, 0};
  *(u16x4*)(out + i) = z;
}

__device__ inline void storev(unsigned short* p, float v) { *p = f2bf(v); }
__device__ inline void storev(float* p, float v) { *p = v; }

// C[M,N] = A[M,K] (row-major, lda) * B[N,K]^T (row-major, ldb)
// grid: (N/128, M/128), block 256 (4 waves, 2x2 of 64x64). m97 structure:
// global_load_lds width=16 staging, linear [128][32] LDS, 2 barriers/K-step.
template <typename OutT>
__global__ __launch_bounds__(256) void gemm_bt(
    const unsigned short* __restrict__ A, int lda,
    const unsigned short* __restrict__ B, int ldb,
    OutT* __restrict__ C, int ldc, int K) {
  __shared__ unsigned short lA[128 * 32];
  __shared__ unsigned short lB[128 * 32];
  const int tid = threadIdx.x;
  const int lane = tid & 63, wave = tid >> 6;
  const int wr = wave >> 1, wc = wave & 1;
  const int l16 = lane & 15, lhi = lane >> 4;
  const long bm = (long)blockIdx.y * 128, bn = (long)blockIdx.x * 128;
  f32x4 acc[4][4];
  #pragma unroll
  for (int m = 0; m < 4; m++)
    #pragma unroll
    for (int n = 0; n < 4; n++) acc[m][n] = (f32x4){0.f, 0.f, 0.f, 0.f};
  // staging: wave w covers 16 rows per call; lane -> (row = w*16 + lane/4, col = (lane&3)*8)
  const int srow = wave * 16 + (lane >> 2);
  const int scol = (lane & 3) * 8;
  const unsigned short* Ag0 = A + (bm + srow) * lda + scol;
  const unsigned short* Ag1 = A + (bm + 64 + srow) * lda + scol;
  const unsigned short* Bg0 = B + (bn + srow) * ldb + scol;
  const unsigned short* Bg1 = B + (bn + 64 + srow) * ldb + scol;
  unsigned short* lA0 = &lA[wave * 512];
  unsigned short* lA1 = &lA[2048 + wave * 512];
  unsigned short* lB0 = &lB[wave * 512];
  unsigned short* lB1 = &lB[2048 + wave * 512];
  for (int k0 = 0; k0 < K; k0 += 32) {
    __syncthreads();
    gload16(Ag0 + k0, lA0);
    gload16(Ag1 + k0, lA1);
    gload16(Bg0 + k0, lB0);
    gload16(Bg1 + k0, lB1);
    __syncthreads();
    bf16x8 af[4], bfv[4];
    #pragma unroll
    for (int m = 0; m < 4; m++)
      af[m] = *(const bf16x8*)&lA[(wr * 64 + m * 16 + l16) * 32 + lhi * 8];
    #pragma unroll
    for (int n = 0; n < 4; n++)
      bfv[n] = *(const bf16x8*)&lB[(wc * 64 + n * 16 + l16) * 32 + lhi * 8];
    #pragma unroll
    for (int m = 0; m < 4; m++)
      #pragma unroll
      for (int n = 0; n < 4; n++)
        acc[m][n] = __builtin_amdgcn_mfma_f32_16x16x32_bf16(af[m], bfv[n], acc[m][n], 0, 0, 0);
  }
  #pragma unroll
  for (int m = 0; m < 4; m++)
    #pragma unroll
    for (int n = 0; n < 4; n++) {
      long row = bm + wr * 64 + m * 16 + lhi * 4;
      long col = bn + wc * 64 + n * 16 + l16;
      #pragma unroll
      for (int i = 0; i < 4; i++) storev(&C[(row + i) * ldc + col], acc[m][n][i]);
    }
}

// in-place rmsnorm of bf16 rows; one block per row
__global__ __launch_bounds__(256) void rmsnorm_kernel(unsigned short* __restrict__ buf,
                                                      const float* __restrict__ w,
                                                      int width, int lda) {
  const int tid = threadIdx.x;
  unsigned short* p = buf + (long)blockIdx.x * lda;
  float ss = 0.f;
  const int nc = width >> 2;
  for (int c = tid; c < nc; c += 256) {
    u16x4 v = *(const u16x4*)(p + c * 4);
    #pragma unroll
    for (int j = 0; j < 4; j++) { float f = bf2f(v[j]); ss += f * f; }
  }
  #pragma unroll
  for (int off = 32; off; off >>= 1) ss += __shfl_xor(ss, off);
  __shared__ float red[4];
  if ((tid & 63) == 0) red[tid >> 6] = ss;
  __syncthreads();
  float tot = red[0] + red[1] + red[2] + red[3];
  float rn = rsqrtf(tot / (float)width + 1e-6f);
  for (int c = tid; c < nc; c += 256) {
    u16x4 v = *(const u16x4*)(p + c * 4);
    u16x4 o;
    #pragma unroll
    for (int j = 0; j < 4; j++) o[j] = f2bf(bf2f(v[j]) * rn * w[c * 4 + j]);
    *(u16x4*)(p + c * 4) = o;
  }
}

__global__ __launch_bounds__(256) void rope_q_kernel(unsigned short* __restrict__ q,
                                                     const float* __restrict__ fr) {
  int idx = blockIdx.x * 256 + threadIdx.x;  // (tok, h, pair)
  int pair = idx & 31, h = (idx >> 5) & 15, tok = idx >> 9;
  int s = tok & (SEQ - 1);
  unsigned short* p = q + (long)tok * QDIM + h * QKH + NOPE_D + pair * 2;
  float c = fr[(s * 32 + pair) * 2 + 0], sn = fr[(s * 32 + pair) * 2 + 1];
  float xr = bf2f(p[0]), xi = bf2f(p[1]);
  p[0] = f2bf(xr * c - xi * sn);
  p[1] = f2bf(xr * sn + xi * c);
}

__global__ __launch_bounds__(256) void rope_k_kernel(unsigned short* __restrict__ cb,
                                                     const float* __restrict__ fr) {
  int idx = blockIdx.x * 256 + threadIdx.x;  // (tok, pair)
  int pair = idx & 31, tok = idx >> 5;
  int s = tok & (SEQ - 1);
  unsigned short* p = cb + (long)tok * CW + KVR + pair * 2;
  float c = fr[(s * 32 + pair) * 2 + 0], sn = fr[(s * 32 + pair) * 2 + 1];
  float xr = bf2f(p[0]), xi = bf2f(p[1]);
  p[0] = f2bf(xr * c - xi * sn);
  p[1] = f2bf(xr * sn + xi * c);
}

// Flash-style causal attention. Flat grid of 512 blocks, 256 thr (4 waves x 32 q-rows,
// QBLK=128). Each wave owns 2 m-frags so K/V fragments are read once per wave
// (halves LDS-pipe traffic vs 8x16). Block i and i+256 map to the SAME (b,h) with
// q-tiles (8+r, 7-r): per-CU work uniform (34 tiles) under 2-blocks/CU allocation.
__global__ __launch_bounds__(256, 2) void attn_kernel(
    const unsigned short* __restrict__ qb,
    const unsigned short* __restrict__ kvb,
    const unsigned short* __restrict__ cb,
    unsigned short* __restrict__ ao) {
  const int bi = blockIdx.x;
  const int r = bi & 7, hb = (bi >> 3) & 31, half = bi >> 8;
  const int h = hb & 15, b = hb >> 4;
  const int qt = (half == 0) ? (8 + r) : (7 - r);
  const int tid = threadIdx.x, wave = tid >> 6, lane = tid & 63;
  const int l16 = lane & 15, lhi = lane >> 4;
  const long tbase = (long)b * SEQ;
  const int q0 = qt * 128;
  __shared__ unsigned short lK[64][200];   // [key][d 0..191]
  __shared__ unsigned short lV[128][72];   // [d][key]  (transposed)
  __shared__ unsigned short lP[4][32][72]; // per-wave P tile (32 q x 64 k)
  const float scale = 0.0721687836f;  // 1/sqrt(192)
  bf16x8 qf[2][6];
  #pragma unroll
  for (int mi = 0; mi < 2; mi++) {
    const unsigned short* qg =
        qb + (tbase + q0 + wave * 32 + mi * 16 + l16) * QDIM + h * QKH;
    #pragma unroll
    for (int d = 0; d < 6; d++) qf[mi][d] = *(const bf16x8*)(qg + d * 32 + lhi * 8);
  }
  f32x4 oacc[2][8];
  #pragma unroll
  for (int mi = 0; mi < 2; mi++)
    #pragma unroll
    for (int n = 0; n < 8; n++) oacc[mi][n] = (f32x4){0.f, 0.f, 0.f, 0.f};
  float mr[2][4], lr[2][4];
  #pragma unroll
  for (int mi = 0; mi < 2; mi++)
    #pragma unroll
    for (int i = 0; i < 4; i++) { mr[mi][i] = -1e30f; lr[mi][i] = 0.f; }

  const int vpr = tid & 31, vd0 = (tid >> 5) * 16;
  const int nkt = 2 * qt + 2;
  for (int kt = 0; kt < nkt; kt++) {
    const int k0 = kt * 64;
    __syncthreads();
    // stage K tile: 64 rows x 192 (128 nope from kv, 64 rope from c); 6 chunks/thread
    #pragma unroll
    for (int it = 0; it < 6; it++) {
      int c = tid + it * 256;
      int row = c / 24, ch = c % 24;
      const unsigned short* src = (ch < 16)
          ? kvb + (tbase + k0 + row) * KVDIM + h * 256 + ch * 8
          : cb + (tbase + k0 + row) * CW + KVR + (ch - 16) * 8;
      *(u16x8*)&lK[row][ch * 8] = *(const u16x8*)src;
    }
    // stage V transposed: thread handles keys {2p,2p+1} x 16 d
    {
      const unsigned short* v0 = kvb + (tbase + k0 + 2 * vpr) * KVDIM + h * 256 + 128 + vd0;
      u16x8 x0 = *(const u16x8*)v0;
      u16x8 x1 = *(const u16x8*)(v0 + 8);
      u16x8 y0 = *(const u16x8*)(v0 + KVDIM);
      u16x8 y1 = *(const u16x8*)(v0 + KVDIM + 8);
      #pragma unroll
      for (int j = 0; j < 8; j++) {
        *(uint32_t*)&lV[vd0 + j][2 * vpr] = (uint32_t)x0[j] | ((uint32_t)y0[j] << 16);
        *(uint32_t*)&lV[vd0 + 8 + j][2 * vpr] = (uint32_t)x1[j] | ((uint32_t)y1[j] << 16);
      }
    }
    __syncthreads();
    // QK^T: wave's 32 q-rows x 64 keys; K-frag read ONCE, used by both m-frags
    f32x4 sc[2][4];
    #pragma unroll
    for (int mi = 0; mi < 2; mi++)
      #pragma unroll
      for (int ks = 0; ks < 4; ks++) sc[mi][ks] = (f32x4){0.f, 0.f, 0.f, 0.f};
    #pragma unroll
    for (int ks = 0; ks < 4; ks++)
      #pragma unroll
      for (int d = 0; d < 6; d++) {
        bf16x8 kf = *(const bf16x8*)&lK[ks * 16 + l16][d * 32 + lhi * 8];
        sc[0][ks] = __builtin_amdgcn_mfma_f32_16x16x32_bf16(qf[0][d], kf, sc[0][ks], 0, 0, 0);
        sc[1][ks] = __builtin_amdgcn_mfma_f32_16x16x32_bf16(qf[1][d], kf, sc[1][ks], 0, 0, 0);
      }
    // scale + causal mask + online softmax, per m-frag
    #pragma unroll
    for (int mi = 0; mi < 2; mi++) {
      #pragma unroll
      for (int ks = 0; ks < 4; ks++)
        #pragma unroll
        for (int i = 0; i < 4; i++) {
          float v = sc[mi][ks][i] * scale;
          if ((k0 + ks * 16 + l16) > (q0 + wave * 32 + mi * 16 + lhi * 4 + i)) v = -1e30f;
          sc[mi][ks][i] = v;
        }
      float fac[4];
      #pragma unroll
      for (int i = 0; i < 4; i++) {
        float mx = fmaxf(fmaxf(sc[mi][0][i], sc[mi][1][i]),
                         fmaxf(sc[mi][2][i], sc[mi][3][i]));
        #pragma unroll
        for (int off = 1; off < 16; off <<= 1) mx = fmaxf(mx, __shfl_xor(mx, off));
        float mn = fmaxf(mr[mi][i], mx);
        fac[i] = exp2f((mr[mi][i] - mn) * 1.44269504f);
        mr[mi][i] = mn;
      }
      float rs[4] = {0.f, 0.f, 0.f, 0.f};
      #pragma unroll
      for (int ks = 0; ks < 4; ks++)
        #pragma unroll
        for (int i = 0; i < 4; i++) {
          float pv = exp2f((sc[mi][ks][i] - mr[mi][i]) * 1.44269504f);
          rs[i] += pv;
          lP[wave][mi * 16 + lhi * 4 + i][ks * 16 + l16] = f2bf(pv);
        }
      #pragma unroll
      for (int i = 0; i < 4; i++) {
        float rr = rs[i];
        #pragma unroll
        for (int off = 1; off < 16; off <<= 1) rr += __shfl_xor(rr, off);
        lr[mi][i] = lr[mi][i] * fac[i] + rr;
      }
      #pragma unroll
      for (int n = 0; n < 8; n++) {
        f32x4 t = oacc[mi][n];
        t[0] *= fac[0]; t[1] *= fac[1]; t[2] *= fac[2]; t[3] *= fac[3];
        oacc[mi][n] = t;
      }
    }
    // PV: O += P(32x64) * V(64x128); V-frag read once, used by both m-frags
    #pragma unroll
    for (int kk = 0; kk < 2; kk++) {
      bf16x8 pf0 = *(const bf16x8*)&lP[wave][l16][kk * 32 + lhi * 8];
      bf16x8 pf1 = *(const bf16x8*)&lP[wave][16 + l16][kk * 32 + lhi * 8];
      #pragma unroll
      for (int n = 0; n < 8; n++) {
        bf16x8 vf = *(const bf16x8*)&lV[n * 16 + l16][kk * 32 + lhi * 8];
        oacc[0][n] = __builtin_amdgcn_mfma_f32_16x16x32_bf16(pf0, vf, oacc[0][n], 0, 0, 0);
        oacc[1][n] = __builtin_amdgcn_mfma_f32_16x16x32_bf16(pf1, vf, oacc[1][n], 0, 0, 0);
      }
    }
  }
  #pragma unroll
  for (int mi = 0; mi < 2; mi++)
    #pragma unroll
    for (int n = 0; n < 8; n++)
      #pragma unroll
      for (int i = 0; i < 4; i++) {
        long row = tbase + q0 + wave * 32 + mi * 16 + lhi * 4 + i;
        ao[row * ODIM + h * 128 + n * 16 + l16] = f2bf(oacc[mi][n][i] / lr[mi][i]);
      }
}

extern "C" void kernel_launch(void* const* d_in, const int* in_sizes, int n_in,
                              void* d_out, int out_size, void* d_ws, size_t ws_size,
                              hipStream_t stream) {
  const float* x = (const float*)d_in[0];
  const float* fr = (const float*)d_in[1];
  const float* wq_a = (const float*)d_in[2];
  const float* qnw = (const float*)d_in[3];
  const float* wq_b = (const float*)d_in[4];
  const float* wkv_a = (const float*)d_in[5];
  const float* kvnw = (const float*)d_in[6];
  const float* wkv_b = (const float*)d_in[7];
  const float* wo = (const float*)d_in[8];
  float* out = (float*)d_out;

  char* ws = (char*)d_ws;
  size_t o = 0;
  unsigned short* xb = (unsigned short*)(ws + o);    o += (size_t)TOK * NDIM * 2;
  unsigned short* wqab = (unsigned short*)(ws + o);  o += (size_t)QR * NDIM * 2;
  unsigned short* wqbb = (unsigned short*)(ws + o);  o += (size_t)QDIM * QR * 2;
  unsigned short* wkvab = (unsigned short*)(ws + o); o += (size_t)CW * NDIM * 2;
  unsigned short* wkvbb = (unsigned short*)(ws + o); o += (size_t)KVDIM * KVR * 2;
  unsigned short* wob = (unsigned short*)(ws + o);   o += (size_t)NDIM * ODIM * 2;
  unsigned short* cq = (unsigned short*)(ws + o);    o += (size_t)TOK * QR * 2;
  unsigned short* qbuf = (unsigned short*)(ws + o);  o += (size_t)TOK * QDIM * 2;
  unsigned short* cbuf = (unsigned short*)(ws + o);  o += (size_t)TOK * CW * 2;
  unsigned short* kvbuf = (unsigned short*)(ws + o); o += (size_t)TOK * KVDIM * 2;
  unsigned short* aout = (unsigned short*)(ws + o);  o += (size_t)TOK * ODIM * 2;

  cvt_kernel<<<(TOK * (long)NDIM) / 1024, 256, 0, stream>>>(x, xb, (long)TOK * NDIM);
  cvt_kernel<<<((long)QR * NDIM) / 1024, 256, 0, stream>>>(wq_a, wqab, (long)QR * NDIM);
  cvt_kernel<<<((long)QDIM * QR) / 1024, 256, 0, stream>>>(wq_b, wqbb, (long)QDIM * QR);
  cvt_kernel<<<((long)576 * NDIM) / 1024, 256, 0, stream>>>(wkv_a, wkvab, (long)576 * NDIM);
  zero_kernel<<<((long)64 * NDIM) / 1024, 256, 0, stream>>>(wkvab + (size_t)576 * NDIM,
                                                            (long)64 * NDIM);
  cvt_kernel<<<((long)KVDIM * KVR) / 1024, 256, 0, stream>>>(wkv_b, wkvbb, (long)KVDIM * KVR);
  cvt_kernel<<<((long)NDIM * ODIM) / 1024, 256, 0, stream>>>(wo, wob, (long)NDIM * ODIM);

  dim3 blk(256);
  gemm_bt<unsigned short><<<dim3(QR / 128, TOK / 128), blk, 0, stream>>>(
      xb, NDIM, wqab, NDIM, cq, QR, NDIM);
  gemm_bt<unsigned short><<<dim3(CW / 128, TOK / 128), blk, 0, stream>>>(
      xb, NDIM, wkvab, NDIM, cbuf, CW, NDIM);
  rmsnorm_kernel<<<TOK, 256, 0, stream>>>(cq, qnw, QR, QR);
  rmsnorm_kernel<<<TOK, 256, 0, stream>>>(cbuf, kvnw, KVR, CW);
  gemm_bt<unsigned short><<<dim3(QDIM / 128, TOK / 128), blk, 0, stream>>>(
      cq, QR, wqbb, QR, qbuf, QDIM, QR);
  gemm_bt<unsigned short><<<dim3(KVDIM / 128, TOK / 128), blk, 0, stream>>>(
      cbuf, CW, wkvbb, KVR, kvbuf, KVDIM, KVR);
  rope_q_kernel<<<(TOK * NH * 32) / 256, 256, 0, stream>>>(qbuf, fr);
  rope_k_kernel<<<(TOK * 32) / 256, 256, 0, stream>>>(cbuf, fr);
  attn_kernel<<<dim3(512, 1, 1), blk, 0, stream>>>(qbuf, kvbuf, cbuf, aout);
  gemm_bt<float><<<dim3(ODIM / 128, TOK / 128), blk, 0, stream>>>(
      aout, ODIM, wob, ODIM, out, ODIM, ODIM);
}

// Round 6
// 519.983 us; speedup vs baseline: 1.2300x; 1.2300x over previous
//
#include <hip/hip_runtime.h>
#include <hip/hip_bf16.h>
#include <math.h>
#include <stdint.h>

#define TOK 4096
#define SEQ 2048
#define NDIM 2048
#define NH 16
#define QR 1536
#define KVR 512
#define NOPE_D 128
#define QKH 192
#define QDIM 3072
#define KVDIM 4096
#define CW 640
#define ODIM 2048

typedef __attribute__((ext_vector_type(4))) float f32x4;
typedef __attribute__((ext_vector_type(8))) __bf16 bf16x8;
typedef __attribute__((ext_vector_type(8))) unsigned short u16x8;
typedef __attribute__((ext_vector_type(4))) unsigned short u16x4;

__device__ inline unsigned short f2bf(float f) {
  union { float f; uint32_t u; } v; v.f = f;
  uint32_t r = (v.u + 0x7FFFu + ((v.u >> 16) & 1u)) >> 16;
  return (unsigned short)r;
}
__device__ inline float bf2f(unsigned short s) {
  union { uint32_t u; float f; } v; v.u = ((uint32_t)s) << 16;
  return v.f;
}

// async global->LDS, 16B per lane. LDS dest is wave-uniform base + lane*16.
__device__ inline void gload16(const void* g, void* l) {
  __builtin_amdgcn_global_load_lds(
      (const __attribute__((address_space(1))) unsigned int*)g,
      (__attribute__((address_space(3))) unsigned int*)l, 16, 0, 0);
}

__global__ __launch_bounds__(256) void cvt_kernel(const float* __restrict__ in,
                                                  unsigned short* __restrict__ out, long n) {
  long i = ((long)blockIdx.x * 256 + threadIdx.x) * 4;
  if (i >= n) return;
  f32x4 v = *(const f32x4*)(in + i);
  u16x4 o;
  #pragma unroll
  for (int j = 0; j < 4; j++) o[j] = f2bf(v[j]);
  *(u16x4*)(out + i) = o;
}

__global__ __launch_bounds__(256) void zero_kernel(unsigned short* __restrict__ out, long n) {
  long i = ((long)blockIdx.x * 256 + threadIdx.x) * 4;
  if (i >= n) return;
  u16x4 z = {0, 0, 0, 0};
  *(u16x4*)(out + i) = z;
}

__device__ inline void storev(unsigned short* p, float v) { *p = f2bf(v); }
__device__ inline void storev(float* p, float v) { *p = v; }

// C[M,N] = A[M,K] (row-major, lda) * B[N,K]^T (row-major, ldb)
// grid: (N/128, M/128), block 256 (4 waves, 2x2 of 64x64). m97 structure:
// global_load_lds width=16 staging, linear [128][32] LDS, 2 barriers/K-step.
template <typename OutT>
__global__ __launch_bounds__(256) void gemm_bt(
    const unsigned short* __restrict__ A, int lda,
    const unsigned short* __restrict__ B, int ldb,
    OutT* __restrict__ C, int ldc, int K) {
  __shared__ unsigned short lA[128 * 32];
  __shared__ unsigned short lB[128 * 32];
  const int tid = threadIdx.x;
  const int lane = tid & 63, wave = tid >> 6;
  const int wr = wave >> 1, wc = wave & 1;
  const int l16 = lane & 15, lhi = lane >> 4;
  const long bm = (long)blockIdx.y * 128, bn = (long)blockIdx.x * 128;
  f32x4 acc[4][4];
  #pragma unroll
  for (int m = 0; m < 4; m++)
    #pragma unroll
    for (int n = 0; n < 4; n++) acc[m][n] = (f32x4){0.f, 0.f, 0.f, 0.f};
  // staging: wave w covers 16 rows per call; lane -> (row = w*16 + lane/4, col = (lane&3)*8)
  const int srow = wave * 16 + (lane >> 2);
  const int scol = (lane & 3) * 8;
  const unsigned short* Ag0 = A + (bm + srow) * lda + scol;
  const unsigned short* Ag1 = A + (bm + 64 + srow) * lda + scol;
  const unsigned short* Bg0 = B + (bn + srow) * ldb + scol;
  const unsigned short* Bg1 = B + (bn + 64 + srow) * ldb + scol;
  unsigned short* lA0 = &lA[wave * 512];
  unsigned short* lA1 = &lA[2048 + wave * 512];
  unsigned short* lB0 = &lB[wave * 512];
  unsigned short* lB1 = &lB[2048 + wave * 512];
  for (int k0 = 0; k0 < K; k0 += 32) {
    __syncthreads();
    gload16(Ag0 + k0, lA0);
    gload16(Ag1 + k0, lA1);
    gload16(Bg0 + k0, lB0);
    gload16(Bg1 + k0, lB1);
    __syncthreads();
    bf16x8 af[4], bfv[4];
    #pragma unroll
    for (int m = 0; m < 4; m++)
      af[m] = *(const bf16x8*)&lA[(wr * 64 + m * 16 + l16) * 32 + lhi * 8];
    #pragma unroll
    for (int n = 0; n < 4; n++)
      bfv[n] = *(const bf16x8*)&lB[(wc * 64 + n * 16 + l16) * 32 + lhi * 8];
    #pragma unroll
    for (int m = 0; m < 4; m++)
      #pragma unroll
      for (int n = 0; n < 4; n++)
        acc[m][n] = __builtin_amdgcn_mfma_f32_16x16x32_bf16(af[m], bfv[n], acc[m][n], 0, 0, 0);
  }
  #pragma unroll
  for (int m = 0; m < 4; m++)
    #pragma unroll
    for (int n = 0; n < 4; n++) {
      long row = bm + wr * 64 + m * 16 + lhi * 4;
      long col = bn + wc * 64 + n * 16 + l16;
      #pragma unroll
      for (int i = 0; i < 4; i++) storev(&C[(row + i) * ldc + col], acc[m][n][i]);
    }
}

// in-place rmsnorm of bf16 rows; one block per row
__global__ __launch_bounds__(256) void rmsnorm_kernel(unsigned short* __restrict__ buf,
                                                      const float* __restrict__ w,
                                                      int width, int lda) {
  const int tid = threadIdx.x;
  unsigned short* p = buf + (long)blockIdx.x * lda;
  float ss = 0.f;
  const int nc = width >> 2;
  for (int c = tid; c < nc; c += 256) {
    u16x4 v = *(const u16x4*)(p + c * 4);
    #pragma unroll
    for (int j = 0; j < 4; j++) { float f = bf2f(v[j]); ss += f * f; }
  }
  #pragma unroll
  for (int off = 32; off; off >>= 1) ss += __shfl_xor(ss, off);
  __shared__ float red[4];
  if ((tid & 63) == 0) red[tid >> 6] = ss;
  __syncthreads();
  float tot = red[0] + red[1] + red[2] + red[3];
  float rn = rsqrtf(tot / (float)width + 1e-6f);
  for (int c = tid; c < nc; c += 256) {
    u16x4 v = *(const u16x4*)(p + c * 4);
    u16x4 o;
    #pragma unroll
    for (int j = 0; j < 4; j++) o[j] = f2bf(bf2f(v[j]) * rn * w[c * 4 + j]);
    *(u16x4*)(p + c * 4) = o;
  }
}

__global__ __launch_bounds__(256) void rope_q_kernel(unsigned short* __restrict__ q,
                                                     const float* __restrict__ fr) {
  int idx = blockIdx.x * 256 + threadIdx.x;  // (tok, h, pair)
  int pair = idx & 31, h = (idx >> 5) & 15, tok = idx >> 9;
  int s = tok & (SEQ - 1);
  unsigned short* p = q + (long)tok * QDIM + h * QKH + NOPE_D + pair * 2;
  float c = fr[(s * 32 + pair) * 2 + 0], sn = fr[(s * 32 + pair) * 2 + 1];
  float xr = bf2f(p[0]), xi = bf2f(p[1]);
  p[0] = f2bf(xr * c - xi * sn);
  p[1] = f2bf(xr * sn + xi * c);
}

__global__ __launch_bounds__(256) void rope_k_kernel(unsigned short* __restrict__ cb,
                                                     const float* __restrict__ fr) {
  int idx = blockIdx.x * 256 + threadIdx.x;  // (tok, pair)
  int pair = idx & 31, tok = idx >> 5;
  int s = tok & (SEQ - 1);
  unsigned short* p = cb + (long)tok * CW + KVR + pair * 2;
  float c = fr[(s * 32 + pair) * 2 + 0], sn = fr[(s * 32 + pair) * 2 + 1];
  float xr = bf2f(p[0]), xi = bf2f(p[1]);
  p[0] = f2bf(xr * c - xi * sn);
  p[1] = f2bf(xr * sn + xi * c);
}

// Flash-style causal attention. 256 blocks (8 pair x 16 h x 2 b), 512 thr
// (8 waves x 16 q-rows, QBLK=128). Each block processes TWO complementary
// q-tiles (pr, 15-pr) sequentially -> every block = exactly 36 KV-tile-works,
// 1 block/CU, zero dispatch tail. lK/lV XOR-swizzled (write+read), next-tile
// K/V reg-prefetch issued before compute (T14).
__global__ __launch_bounds__(512, 2) void attn_kernel(
    const unsigned short* __restrict__ qb,
    const unsigned short* __restrict__ kvb,
    const unsigned short* __restrict__ cb,
    unsigned short* __restrict__ ao) {
  const int bi = blockIdx.x;
  const int pr = bi & 7, h = (bi >> 3) & 15, b = bi >> 7;
  const int tid = threadIdx.x, wave = tid >> 6, lane = tid & 63;
  const int l16 = lane & 15, lhi = lane >> 4;
  const long tbase = (long)b * SEQ;
  __shared__ unsigned short lK[64][192];   // [key][d], col^=(row&7)*8 swizzle
  __shared__ unsigned short lV[128][64];   // [d][key] transposed, swizzled
  __shared__ unsigned short lP[8][16][72]; // per-wave P tile
  const float scale = 0.0721687836f;  // 1/sqrt(192)
  const int sw = l16 & 7;             // read-side swizzle key
  // prefetch registers
  u16x8 kreg[3];
  u16x8 vreg[2];
  const int vpr = tid & 31, vd0 = (tid >> 5) * 8;

  auto load_tile = [&](int k0) {
    #pragma unroll
    for (int it = 0; it < 3; it++) {
      int c = tid + it * 512;
      int row = c / 24, ch = c % 24;
      const unsigned short* src = (ch < 16)
          ? kvb + (tbase + k0 + row) * KVDIM + h * 256 + ch * 8
          : cb + (tbase + k0 + row) * CW + KVR + (ch - 16) * 8;
      kreg[it] = *(const u16x8*)src;
    }
    const unsigned short* v0 = kvb + (tbase + k0 + 2 * vpr) * KVDIM + h * 256 + 128 + vd0;
    vreg[0] = *(const u16x8*)v0;
    vreg[1] = *(const u16x8*)(v0 + KVDIM);
  };
  auto write_tile = [&]() {
    #pragma unroll
    for (int it = 0; it < 3; it++) {
      int c = tid + it * 512;
      int row = c / 24, ch = c % 24;
      *(u16x8*)&lK[row][(ch ^ (row & 7)) * 8] = kreg[it];
    }
    #pragma unroll
    for (int j = 0; j < 8; j++)
      *(uint32_t*)&lV[vd0 + j][(2 * vpr) ^ (j << 3)] =
          (uint32_t)vreg[0][j] | ((uint32_t)vreg[1][j] << 16);
  };

  for (int sub = 0; sub < 2; sub++) {
    const int qt = sub ? (15 - pr) : pr;
    const int q0 = qt * 128;
    bf16x8 qf[6];
    {
      const unsigned short* qg = qb + (tbase + q0 + wave * 16 + l16) * QDIM + h * QKH;
      #pragma unroll
      for (int d = 0; d < 6; d++) qf[d] = *(const bf16x8*)(qg + d * 32 + lhi * 8);
    }
    f32x4 oacc[8];
    #pragma unroll
    for (int n = 0; n < 8; n++) oacc[n] = (f32x4){0.f, 0.f, 0.f, 0.f};
    float mr[4], lr[4];
    #pragma unroll
    for (int i = 0; i < 4; i++) { mr[i] = -1e30f; lr[i] = 0.f; }

    const int nkt = 2 * qt + 2;
    load_tile(0);
    for (int kt = 0; kt < nkt; kt++) {
      const int k0 = kt * 64;
      __syncthreads();          // all waves done reading previous tile's LDS
      write_tile();
      __syncthreads();          // staged tile visible
      if (kt + 1 < nkt) load_tile((kt + 1) * 64);  // flies during compute
      // QK^T: wave's 16 q-rows x 64 keys
      f32x4 sc[4];
      #pragma unroll
      for (int ks = 0; ks < 4; ks++) {
        sc[ks] = (f32x4){0.f, 0.f, 0.f, 0.f};
        #pragma unroll
        for (int d = 0; d < 6; d++) {
          bf16x8 kf = *(const bf16x8*)&lK[ks * 16 + l16][((4 * d + lhi) ^ sw) * 8];
          sc[ks] = __builtin_amdgcn_mfma_f32_16x16x32_bf16(qf[d], kf, sc[ks], 0, 0, 0);
        }
      }
      // scale + causal mask
      #pragma unroll
      for (int ks = 0; ks < 4; ks++)
        #pragma unroll
        for (int i = 0; i < 4; i++) {
          float v = sc[ks][i] * scale;
          if ((k0 + ks * 16 + l16) > (q0 + wave * 16 + lhi * 4 + i)) v = -1e30f;
          sc[ks][i] = v;
        }
      float fac[4];
      #pragma unroll
      for (int i = 0; i < 4; i++) {
        float mx = fmaxf(fmaxf(sc[0][i], sc[1][i]), fmaxf(sc[2][i], sc[3][i]));
        #pragma unroll
        for (int off = 1; off < 16; off <<= 1) mx = fmaxf(mx, __shfl_xor(mx, off));
        float mn = fmaxf(mr[i], mx);
        fac[i] = exp2f((mr[i] - mn) * 1.44269504f);
        mr[i] = mn;
      }
      float rs[4] = {0.f, 0.f, 0.f, 0.f};
      #pragma unroll
      for (int ks = 0; ks < 4; ks++)
        #pragma unroll
        for (int i = 0; i < 4; i++) {
          float pv = exp2f((sc[ks][i] - mr[i]) * 1.44269504f);
          rs[i] += pv;
          lP[wave][lhi * 4 + i][ks * 16 + l16] = f2bf(pv);
        }
      #pragma unroll
      for (int i = 0; i < 4; i++) {
        float r = rs[i];
        #pragma unroll
        for (int off = 1; off < 16; off <<= 1) r += __shfl_xor(r, off);
        lr[i] = lr[i] * fac[i] + r;
      }
      #pragma unroll
      for (int n = 0; n < 8; n++) {
        f32x4 t = oacc[n];
        t[0] *= fac[0]; t[1] *= fac[1]; t[2] *= fac[2]; t[3] *= fac[3];
        oacc[n] = t;
      }
      // PV: O += P(16x64) * V(64x128)
      #pragma unroll
      for (int kk = 0; kk < 2; kk++) {
        bf16x8 pf = *(const bf16x8*)&lP[wave][l16][kk * 32 + lhi * 8];
        #pragma unroll
        for (int n = 0; n < 8; n++) {
          bf16x8 vf = *(const bf16x8*)&lV[n * 16 + l16][((kk * 4 + lhi) ^ sw) * 8];
          oacc[n] = __builtin_amdgcn_mfma_f32_16x16x32_bf16(pf, vf, oacc[n], 0, 0, 0);
        }
      }
    }
    #pragma unroll
    for (int n = 0; n < 8; n++)
      #pragma unroll
      for (int i = 0; i < 4; i++) {
        long row = tbase + q0 + wave * 16 + lhi * 4 + i;
        ao[row * ODIM + h * 128 + n * 16 + l16] = f2bf(oacc[n][i] / lr[i]);
      }
  }
}

extern "C" void kernel_launch(void* const* d_in, const int* in_sizes, int n_in,
                              void* d_out, int out_size, void* d_ws, size_t ws_size,
                              hipStream_t stream) {
  const float* x = (const float*)d_in[0];
  const float* fr = (const float*)d_in[1];
  const float* wq_a = (const float*)d_in[2];
  const float* qnw = (const float*)d_in[3];
  const float* wq_b = (const float*)d_in[4];
  const float* wkv_a = (const float*)d_in[5];
  const float* kvnw = (const float*)d_in[6];
  const float* wkv_b = (const float*)d_in[7];
  const float* wo = (const float*)d_in[8];
  float* out = (float*)d_out;

  char* ws = (char*)d_ws;
  size_t o = 0;
  unsigned short* xb = (unsigned short*)(ws + o);    o += (size_t)TOK * NDIM * 2;
  unsigned short* wqab = (unsigned short*)(ws + o);  o += (size_t)QR * NDIM * 2;
  unsigned short* wqbb = (unsigned short*)(ws + o);  o += (size_t)QDIM * QR * 2;
  unsigned short* wkvab = (unsigned short*)(ws + o); o += (size_t)CW * NDIM * 2;
  unsigned short* wkvbb = (unsigned short*)(ws + o); o += (size_t)KVDIM * KVR * 2;
  unsigned short* wob = (unsigned short*)(ws + o);   o += (size_t)NDIM * ODIM * 2;
  unsigned short* cq = (unsigned short*)(ws + o);    o += (size_t)TOK * QR * 2;
  unsigned short* qbuf = (unsigned short*)(ws + o);  o += (size_t)TOK * QDIM * 2;
  unsigned short* cbuf = (unsigned short*)(ws + o);  o += (size_t)TOK * CW * 2;
  unsigned short* kvbuf = (unsigned short*)(ws + o); o += (size_t)TOK * KVDIM * 2;
  unsigned short* aout = (unsigned short*)(ws + o);  o += (size_t)TOK * ODIM * 2;

  cvt_kernel<<<(TOK * (long)NDIM) / 1024, 256, 0, stream>>>(x, xb, (long)TOK * NDIM);
  cvt_kernel<<<((long)QR * NDIM) / 1024, 256, 0, stream>>>(wq_a, wqab, (long)QR * NDIM);
  cvt_kernel<<<((long)QDIM * QR) / 1024, 256, 0, stream>>>(wq_b, wqbb, (long)QDIM * QR);
  cvt_kernel<<<((long)576 * NDIM) / 1024, 256, 0, stream>>>(wkv_a, wkvab, (long)576 * NDIM);
  zero_kernel<<<((long)64 * NDIM) / 1024, 256, 0, stream>>>(wkvab + (size_t)576 * NDIM,
                                                            (long)64 * NDIM);
  cvt_kernel<<<((long)KVDIM * KVR) / 1024, 256, 0, stream>>>(wkv_b, wkvbb, (long)KVDIM * KVR);
  cvt_kernel<<<((long)NDIM * ODIM) / 1024, 256, 0, stream>>>(wo, wob, (long)NDIM * ODIM);

  dim3 blk(256);
  gemm_bt<unsigned short><<<dim3(QR / 128, TOK / 128), blk, 0, stream>>>(
      xb, NDIM, wqab, NDIM, cq, QR, NDIM);
  gemm_bt<unsigned short><<<dim3(CW / 128, TOK / 128), blk, 0, stream>>>(
      xb, NDIM, wkvab, NDIM, cbuf, CW, NDIM);
  rmsnorm_kernel<<<TOK, 256, 0, stream>>>(cq, qnw, QR, QR);
  rmsnorm_kernel<<<TOK, 256, 0, stream>>>(cbuf, kvnw, KVR, CW);
  gemm_bt<unsigned short><<<dim3(QDIM / 128, TOK / 128), blk, 0, stream>>>(
      cq, QR, wqbb, QR, qbuf, QDIM, QR);
  gemm_bt<unsigned short><<<dim3(KVDIM / 128, TOK / 128), blk, 0, stream>>>(
      cbuf, CW, wkvbb, KVR, kvbuf, KVDIM, KVR);
  rope_q_kernel<<<(TOK * NH * 32) / 256, 256, 0, stream>>>(qbuf, fr);
  rope_k_kernel<<<(TOK * 32) / 256, 256, 0, stream>>>(cbuf, fr);
  attn_kernel<<<dim3(256, 1, 1), 512, 0, stream>>>(qbuf, kvbuf, cbuf, aout);
  gemm_bt<float><<<dim3(ODIM / 128, TOK / 128), blk, 0, stream>>>(
      aout, ODIM, wob, ODIM, out, ODIM, ODIM);
}

// Round 8
// 463.526 us; speedup vs baseline: 1.3798x; 1.1218x over previous
//
#include <hip/hip_runtime.h>
#include <hip/hip_bf16.h>
#include <math.h>
#include <stdint.h>

#define TOK 4096
#define SEQ 2048
#define NDIM 2048
#define NH 16
#define QR 1536
#define KVR 512
#define NOPE_D 128
#define QKH 192
#define QDIM 3072
#define KVDIM 4096
#define CSTR 2176   // merged c-buffer row stride: 1536 (q latent) + 640 (kv latent + rope)
#define ODIM 2048

typedef __attribute__((ext_vector_type(4))) float f32x4;
typedef __attribute__((ext_vector_type(8))) __bf16 bf16x8;
typedef __attribute__((ext_vector_type(8))) unsigned short u16x8;
typedef __attribute__((ext_vector_type(4))) unsigned short u16x4;

__device__ inline unsigned short f2bf(float f) {
  union { float f; uint32_t u; } v; v.f = f;
  uint32_t r = (v.u + 0x7FFFu + ((v.u >> 16) & 1u)) >> 16;
  return (unsigned short)r;
}
__device__ inline float bf2f(unsigned short s) {
  union { uint32_t u; float f; } v; v.u = ((uint32_t)s) << 16;
  return v.f;
}

// async global->LDS, 16B per lane. LDS dest is wave-uniform base + lane*16.
__device__ inline void gload16(const void* g, void* l) {
  __builtin_amdgcn_global_load_lds(
      (const __attribute__((address_space(1))) unsigned int*)g,
      (__attribute__((address_space(3))) unsigned int*)l, 16, 0, 0);
}

__global__ __launch_bounds__(256) void cvt_kernel(const float* __restrict__ in,
                                                  unsigned short* __restrict__ out, long n) {
  long i = ((long)blockIdx.x * 256 + threadIdx.x) * 4;
  if (i >= n) return;
  f32x4 v = *(const f32x4*)(in + i);
  u16x4 o;
  #pragma unroll
  for (int j = 0; j < 4; j++) o[j] = f2bf(v[j]);
  *(u16x4*)(out + i) = o;
}

__global__ __launch_bounds__(256) void zero_kernel(unsigned short* __restrict__ out, long n) {
  long i = ((long)blockIdx.x * 256 + threadIdx.x) * 4;
  if (i >= n) return;
  u16x4 z = {0, 0, 0, 0};
  *(u16x4*)(out + i) = z;
}

__device__ inline void storev(unsigned short* p, float v) { *p = f2bf(v); }
__device__ inline void storev(float* p, float v) { *p = v; }

// C[M,N] = A[M,K] (row-major, lda) * B[N,K]^T (row-major, ldb)
// grid: (N/128, M/128), block 256 (4 waves, 2x2 of 64x64).
// m97 staging (global_load_lds width=16) + 2-phase double-buffer with COUNTED
// vmcnt(4): next K-tile's loads issued before computing current tile, kept in
// flight across raw s_barriers (no vmcnt(0) drain in the loop). Covers the
// load latency that is exposed at 1-2 blocks/CU residency.
template <typename OutT>
__global__ __launch_bounds__(256) void gemm_bt(
    const unsigned short* __restrict__ A, int lda,
    const unsigned short* __restrict__ B, int ldb,
    OutT* __restrict__ C, int ldc, int K) {
  __shared__ unsigned short lA[2][128 * 32];
  __shared__ unsigned short lB[2][128 * 32];
  const int tid = threadIdx.x;
  const int lane = tid & 63, wave = tid >> 6;
  const int wr = wave >> 1, wc = wave & 1;
  const int l16 = lane & 15, lhi = lane >> 4;
  const long bm = (long)blockIdx.y * 128, bn = (long)blockIdx.x * 128;
  f32x4 acc[4][4];
  #pragma unroll
  for (int m = 0; m < 4; m++)
    #pragma unroll
    for (int n = 0; n < 4; n++) acc[m][n] = (f32x4){0.f, 0.f, 0.f, 0.f};
  // staging: wave w covers 16 rows per call; lane -> (row = w*16 + lane/4, col = (lane&3)*8)
  const int srow = wave * 16 + (lane >> 2);
  const int scol = (lane & 3) * 8;
  const unsigned short* Ag0 = A + (bm + srow) * lda + scol;
  const unsigned short* Ag1 = A + (bm + 64 + srow) * lda + scol;
  const unsigned short* Bg0 = B + (bn + srow) * ldb + scol;
  const unsigned short* Bg1 = B + (bn + 64 + srow) * ldb + scol;
  auto stage = [&](int buf, int k0) {
    gload16(Ag0 + k0, &lA[buf][wave * 512]);
    gload16(Ag1 + k0, &lA[buf][2048 + wave * 512]);
    gload16(Bg0 + k0, &lB[buf][wave * 512]);
    gload16(Bg1 + k0, &lB[buf][2048 + wave * 512]);
  };
  const int nt = K >> 5;
  stage(0, 0);
  for (int t = 0; t < nt; ++t) {
    const int cur = t & 1;
    if (t + 1 < nt) {
      stage(cur ^ 1, (t + 1) * 32);                  // prefetch flies over compute
      asm volatile("s_waitcnt vmcnt(4)" ::: "memory");  // cur's 4 loads done
    } else {
      asm volatile("s_waitcnt vmcnt(0)" ::: "memory");
    }
    __builtin_amdgcn_s_barrier();                    // cur staged for all waves
    bf16x8 af[4], bfv[4];
    #pragma unroll
    for (int m = 0; m < 4; m++)
      af[m] = *(const bf16x8*)&lA[cur][(wr * 64 + m * 16 + l16) * 32 + lhi * 8];
    #pragma unroll
    for (int n = 0; n < 4; n++)
      bfv[n] = *(const bf16x8*)&lB[cur][(wc * 64 + n * 16 + l16) * 32 + lhi * 8];
    #pragma unroll
    for (int m = 0; m < 4; m++)
      #pragma unroll
      for (int n = 0; n < 4; n++)
        acc[m][n] = __builtin_amdgcn_mfma_f32_16x16x32_bf16(af[m], bfv[n], acc[m][n], 0, 0, 0);
    asm volatile("s_waitcnt lgkmcnt(0)" ::: "memory");  // my reads of cur complete
    __builtin_amdgcn_sched_barrier(0);
    __builtin_amdgcn_s_barrier();                    // cur free to overwrite at t+2
  }
  #pragma unroll
  for (int m = 0; m < 4; m++)
    #pragma unroll
    for (int n = 0; n < 4; n++) {
      long row = bm + wr * 64 + m * 16 + lhi * 4;
      long col = bn + wc * 64 + n * 16 + l16;
      #pragma unroll
      for (int i = 0; i < 4; i++) storev(&C[(row + i) * ldc + col], acc[m][n][i]);
    }
}

// in-place rmsnorm of bf16 rows; one block per row
__global__ __launch_bounds__(256) void rmsnorm_kernel(unsigned short* __restrict__ buf,
                                                      const float* __restrict__ w,
                                                      int width, int lda) {
  const int tid = threadIdx.x;
  unsigned short* p = buf + (long)blockIdx.x * lda;
  float ss = 0.f;
  const int nc = width >> 2;
  for (int c = tid; c < nc; c += 256) {
    u16x4 v = *(const u16x4*)(p + c * 4);
    #pragma unroll
    for (int j = 0; j < 4; j++) { float f = bf2f(v[j]); ss += f * f; }
  }
  #pragma unroll
  for (int off = 32; off; off >>= 1) ss += __shfl_xor(ss, off);
  __shared__ float red[4];
  if ((tid & 63) == 0) red[tid >> 6] = ss;
  __syncthreads();
  float tot = red[0] + red[1] + red[2] + red[3];
  float rn = rsqrtf(tot / (float)width + 1e-6f);
  for (int c = tid; c < nc; c += 256) {
    u16x4 v = *(const u16x4*)(p + c * 4);
    u16x4 o;
    #pragma unroll
    for (int j = 0; j < 4; j++) o[j] = f2bf(bf2f(v[j]) * rn * w[c * 4 + j]);
    *(u16x4*)(p + c * 4) = o;
  }
}

__global__ __launch_bounds__(256) void rope_q_kernel(unsigned short* __restrict__ q,
                                                     const float* __restrict__ fr) {
  int idx = blockIdx.x * 256 + threadIdx.x;  // (tok, h, pair)
  int pair = idx & 31, h = (idx >> 5) & 15, tok = idx >> 9;
  int s = tok & (SEQ - 1);
  unsigned short* p = q + (long)tok * QDIM + h * QKH + NOPE_D + pair * 2;
  float c = fr[(s * 32 + pair) * 2 + 0], sn = fr[(s * 32 + pair) * 2 + 1];
  float xr = bf2f(p[0]), xi = bf2f(p[1]);
  p[0] = f2bf(xr * c - xi * sn);
  p[1] = f2bf(xr * sn + xi * c);
}

// cb points at the kv-latent sub-buffer (row stride CSTR)
__global__ __launch_bounds__(256) void rope_k_kernel(unsigned short* __restrict__ cb,
                                                     const float* __restrict__ fr) {
  int idx = blockIdx.x * 256 + threadIdx.x;  // (tok, pair)
  int pair = idx & 31, tok = idx >> 5;
  int s = tok & (SEQ - 1);
  unsigned short* p = cb + (long)tok * CSTR + KVR + pair * 2;
  float c = fr[(s * 32 + pair) * 2 + 0], sn = fr[(s * 32 + pair) * 2 + 1];
  float xr = bf2f(p[0]), xi = bf2f(p[1]);
  p[0] = f2bf(xr * c - xi * sn);
  p[1] = f2bf(xr * sn + xi * c);
}

// Flash-style causal attention. 256 blocks (8 pair x 16 h x 2 b), 512 thr
// (8 waves x 16 q-rows, QBLK=128). Each block processes TWO complementary
// q-tiles (pr, 15-pr) sequentially -> every block = exactly 36 KV-tile-works,
// 1 block/CU, zero dispatch tail. lK/lV XOR-swizzled (write+read), next-tile
// K/V reg-prefetch issued before compute (T14). Causal mask applied only for
// tiles overlapping the diagonal (kt >= 2*qt; block-uniform branch).
__global__ __launch_bounds__(512, 2) void attn_kernel(
    const unsigned short* __restrict__ qb,
    const unsigned short* __restrict__ kvb,
    const unsigned short* __restrict__ cb,
    unsigned short* __restrict__ ao) {
  const int bi = blockIdx.x;
  const int pr = bi & 7, h = (bi >> 3) & 15, b = bi >> 7;
  const int tid = threadIdx.x, wave = tid >> 6, lane = tid & 63;
  const int l16 = lane & 15, lhi = lane >> 4;
  const long tbase = (long)b * SEQ;
  __shared__ unsigned short lK[64][192];   // [key][d], col^=(row&7)*8 swizzle
  __shared__ unsigned short lV[128][64];   // [d][key] transposed, swizzled
  __shared__ unsigned short lP[8][16][72]; // per-wave P tile
  const float scale = 0.0721687836f;  // 1/sqrt(192)
  const int sw = l16 & 7;             // read-side swizzle key
  // prefetch registers
  u16x8 kreg[3];
  u16x8 vreg[2];
  const int vpr = tid & 31, vd0 = (tid >> 5) * 8;

  auto load_tile = [&](int k0) {
    #pragma unroll
    for (int it = 0; it < 3; it++) {
      int c = tid + it * 512;
      int row = c / 24, ch = c % 24;
      const unsigned short* src = (ch < 16)
          ? kvb + (tbase + k0 + row) * KVDIM + h * 256 + ch * 8
          : cb + (tbase + k0 + row) * CSTR + KVR + (ch - 16) * 8;
      kreg[it] = *(const u16x8*)src;
    }
    const unsigned short* v0 = kvb + (tbase + k0 + 2 * vpr) * KVDIM + h * 256 + 128 + vd0;
    vreg[0] = *(const u16x8*)v0;
    vreg[1] = *(const u16x8*)(v0 + KVDIM);
  };
  auto write_tile = [&]() {
    #pragma unroll
    for (int it = 0; it < 3; it++) {
      int c = tid + it * 512;
      int row = c / 24, ch = c % 24;
      *(u16x8*)&lK[row][(ch ^ (row & 7)) * 8] = kreg[it];
    }
    #pragma unroll
    for (int j = 0; j < 8; j++)
      *(uint32_t*)&lV[vd0 + j][(2 * vpr) ^ (j << 3)] =
          (uint32_t)vreg[0][j] | ((uint32_t)vreg[1][j] << 16);
  };

  for (int sub = 0; sub < 2; sub++) {
    const int qt = sub ? (15 - pr) : pr;
    const int q0 = qt * 128;
    bf16x8 qf[6];
    {
      const unsigned short* qg = qb + (tbase + q0 + wave * 16 + l16) * QDIM + h * QKH;
      #pragma unroll
      for (int d = 0; d < 6; d++) qf[d] = *(const bf16x8*)(qg + d * 32 + lhi * 8);
    }
    f32x4 oacc[8];
    #pragma unroll
    for (int n = 0; n < 8; n++) oacc[n] = (f32x4){0.f, 0.f, 0.f, 0.f};
    float mr[4], lr[4];
    #pragma unroll
    for (int i = 0; i < 4; i++) { mr[i] = -1e30f; lr[i] = 0.f; }
    const int qrow = q0 + wave * 16 + lhi * 4;

    const int nkt = 2 * qt + 2;
    load_tile(0);
    for (int kt = 0; kt < nkt; kt++) {
      const int k0 = kt * 64;
      __syncthreads();          // all waves done reading previous tile's LDS
      write_tile();
      __syncthreads();          // staged tile visible
      if (kt + 1 < nkt) load_tile((kt + 1) * 64);  // flies during compute
      // QK^T: wave's 16 q-rows x 64 keys
      f32x4 sc[4];
      #pragma unroll
      for (int ks = 0; ks < 4; ks++) {
        sc[ks] = (f32x4){0.f, 0.f, 0.f, 0.f};
        #pragma unroll
        for (int d = 0; d < 6; d++) {
          bf16x8 kf = *(const bf16x8*)&lK[ks * 16 + l16][((4 * d + lhi) ^ sw) * 8];
          sc[ks] = __builtin_amdgcn_mfma_f32_16x16x32_bf16(qf[d], kf, sc[ks], 0, 0, 0);
        }
      }
      // scale always; causal mask only when the tile can touch the diagonal
      #pragma unroll
      for (int ks = 0; ks < 4; ks++)
        #pragma unroll
        for (int i = 0; i < 4; i++) sc[ks][i] *= scale;
      if (kt >= 2 * qt) {
        #pragma unroll
        for (int ks = 0; ks < 4; ks++) {
          const int kcol = k0 + ks * 16 + l16;
          #pragma unroll
          for (int i = 0; i < 4; i++)
            if (kcol > qrow + i) sc[ks][i] = -1e30f;
        }
      }
      float fac[4];
      #pragma unroll
      for (int i = 0; i < 4; i++) {
        float mx = fmaxf(fmaxf(sc[0][i], sc[1][i]), fmaxf(sc[2][i], sc[3][i]));
        #pragma unroll
        for (int off = 1; off < 16; off <<= 1) mx = fmaxf(mx, __shfl_xor(mx, off));
        float mn = fmaxf(mr[i], mx);
        fac[i] = exp2f((mr[i] - mn) * 1.44269504f);
        mr[i] = mn;
      }
      float rs[4] = {0.f, 0.f, 0.f, 0.f};
      #pragma unroll
      for (int ks = 0; ks < 4; ks++)
        #pragma unroll
        for (int i = 0; i < 4; i++) {
          float pv = exp2f((sc[ks][i] - mr[i]) * 1.44269504f);
          rs[i] += pv;
          lP[wave][lhi * 4 + i][ks * 16 + l16] = f2bf(pv);
        }
      #pragma unroll
      for (int i = 0; i < 4; i++) {
        float r = rs[i];
        #pragma unroll
        for (int off = 1; off < 16; off <<= 1) r += __shfl_xor(r, off);
        lr[i] = lr[i] * fac[i] + r;
      }
      #pragma unroll
      for (int n = 0; n < 8; n++) {
        f32x4 t = oacc[n];
        t[0] *= fac[0]; t[1] *= fac[1]; t[2] *= fac[2]; t[3] *= fac[3];
        oacc[n] = t;
      }
      // PV: O += P(16x64) * V(64x128)
      #pragma unroll
      for (int kk = 0; kk < 2; kk++) {
        bf16x8 pf = *(const bf16x8*)&lP[wave][l16][kk * 32 + lhi * 8];
        #pragma unroll
        for (int n = 0; n < 8; n++) {
          bf16x8 vf = *(const bf16x8*)&lV[n * 16 + l16][((kk * 4 + lhi) ^ sw) * 8];
          oacc[n] = __builtin_amdgcn_mfma_f32_16x16x32_bf16(pf, vf, oacc[n], 0, 0, 0);
        }
      }
    }
    #pragma unroll
    for (int n = 0; n < 8; n++)
      #pragma unroll
      for (int i = 0; i < 4; i++) {
        long row = tbase + q0 + wave * 16 + lhi * 4 + i;
        ao[row * ODIM + h * 128 + n * 16 + l16] = f2bf(oacc[n][i] / lr[i]);
      }
  }
}

extern "C" void kernel_launch(void* const* d_in, const int* in_sizes, int n_in,
                              void* d_out, int out_size, void* d_ws, size_t ws_size,
                              hipStream_t stream) {
  const float* x = (const float*)d_in[0];
  const float* fr = (const float*)d_in[1];
  const float* wq_a = (const float*)d_in[2];
  const float* qnw = (const float*)d_in[3];
  const float* wq_b = (const float*)d_in[4];
  const float* wkv_a = (const float*)d_in[5];
  const float* kvnw = (const float*)d_in[6];
  const float* wkv_b = (const float*)d_in[7];
  const float* wo = (const float*)d_in[8];
  float* out = (float*)d_out;

  char* ws = (char*)d_ws;
  size_t o = 0;
  unsigned short* xb = (unsigned short*)(ws + o);    o += (size_t)TOK * NDIM * 2;
  unsigned short* wcomb = (unsigned short*)(ws + o); o += (size_t)CSTR * NDIM * 2;
  unsigned short* wqbb = (unsigned short*)(ws + o);  o += (size_t)QDIM * QR * 2;
  unsigned short* wkvbb = (unsigned short*)(ws + o); o += (size_t)KVDIM * KVR * 2;
  unsigned short* wob = (unsigned short*)(ws + o);   o += (size_t)NDIM * ODIM * 2;
  unsigned short* cw = (unsigned short*)(ws + o);    o += (size_t)TOK * CSTR * 2;
  unsigned short* qbuf = (unsigned short*)(ws + o);  o += (size_t)TOK * QDIM * 2;
  unsigned short* kvbuf = (unsigned short*)(ws + o); o += (size_t)TOK * KVDIM * 2;
  unsigned short* aout = (unsigned short*)(ws + o);  o += (size_t)TOK * ODIM * 2;
  unsigned short* ckv = cw + QR;  // kv-latent+rope sub-buffer, row stride CSTR

  cvt_kernel<<<(TOK * (long)NDIM) / 1024, 256, 0, stream>>>(x, xb, (long)TOK * NDIM);
  cvt_kernel<<<((long)QR * NDIM) / 1024, 256, 0, stream>>>(wq_a, wcomb, (long)QR * NDIM);
  cvt_kernel<<<((long)576 * NDIM) / 1024, 256, 0, stream>>>(
      wkv_a, wcomb + (size_t)QR * NDIM, (long)576 * NDIM);
  zero_kernel<<<((long)64 * NDIM) / 1024, 256, 0, stream>>>(
      wcomb + (size_t)(QR + 576) * NDIM, (long)64 * NDIM);
  cvt_kernel<<<((long)QDIM * QR) / 1024, 256, 0, stream>>>(wq_b, wqbb, (long)QDIM * QR);
  cvt_kernel<<<((long)KVDIM * KVR) / 1024, 256, 0, stream>>>(wkv_b, wkvbb, (long)KVDIM * KVR);
  cvt_kernel<<<((long)NDIM * ODIM) / 1024, 256, 0, stream>>>(wo, wob, (long)NDIM * ODIM);

  dim3 blk(256);
  // merged q-latent + kv-latent projection: N = 2176
  gemm_bt<unsigned short><<<dim3(CSTR / 128, TOK / 128), blk, 0, stream>>>(
      xb, NDIM, wcomb, NDIM, cw, CSTR, NDIM);
  rmsnorm_kernel<<<TOK, 256, 0, stream>>>(cw, qnw, QR, CSTR);
  rmsnorm_kernel<<<TOK, 256, 0, stream>>>(ckv, kvnw, KVR, CSTR);
  gemm_bt<unsigned short><<<dim3(QDIM / 128, TOK / 128), blk, 0, stream>>>(
      cw, CSTR, wqbb, QR, qbuf, QDIM, QR);
  gemm_bt<unsigned short><<<dim3(KVDIM / 128, TOK / 128), blk, 0, stream>>>(
      ckv, CSTR, wkvbb, KVR, kvbuf, KVDIM, KVR);
  rope_q_kernel<<<(TOK * NH * 32) / 256, 256, 0, stream>>>(qbuf, fr);
  rope_k_kernel<<<(TOK * 32) / 256, 256, 0, stream>>>(ckv, fr);
  attn_kernel<<<dim3(256, 1, 1), 512, 0, stream>>>(qbuf, kvbuf, ckv, aout);
  gemm_bt<float><<<dim3(ODIM / 128, TOK / 128), blk, 0, stream>>>(
      aout, ODIM, wob, ODIM, out, ODIM, ODIM);
}

// Round 9
// 440.700 us; speedup vs baseline: 1.4513x; 1.0518x over previous
//
#include <hip/hip_runtime.h>
#include <hip/hip_bf16.h>
#include <math.h>
#include <stdint.h>

#define TOK 4096
#define SEQ 2048
#define NDIM 2048
#define NH 16
#define QR 1536
#define KVR 512
#define NOPE_D 128
#define QKH 192
#define QDIM 3072
#define KVDIM 4096
#define CSTR 2176   // merged c-buffer row stride: 1536 (q latent) + 640 (kv latent + rope)
#define ODIM 2048

typedef __attribute__((ext_vector_type(4))) float f32x4;
typedef __attribute__((ext_vector_type(8))) __bf16 bf16x8;
typedef __attribute__((ext_vector_type(8))) unsigned short u16x8;
typedef __attribute__((ext_vector_type(4))) unsigned short u16x4;

__device__ inline unsigned short f2bf(float f) {
  union { float f; uint32_t u; } v; v.f = f;
  uint32_t r = (v.u + 0x7FFFu + ((v.u >> 16) & 1u)) >> 16;
  return (unsigned short)r;
}
__device__ inline float bf2f(unsigned short s) {
  union { uint32_t u; float f; } v; v.u = ((uint32_t)s) << 16;
  return v.f;
}

// async global->LDS, 16B per lane. LDS dest is wave-uniform base + lane*16.
__device__ inline void gload16(const void* g, void* l) {
  __builtin_amdgcn_global_load_lds(
      (const __attribute__((address_space(1))) unsigned int*)g,
      (__attribute__((address_space(3))) unsigned int*)l, 16, 0, 0);
}

__global__ __launch_bounds__(256) void cvt_kernel(const float* __restrict__ in,
                                                  unsigned short* __restrict__ out, long n) {
  long i = ((long)blockIdx.x * 256 + threadIdx.x) * 4;
  if (i >= n) return;
  f32x4 v = *(const f32x4*)(in + i);
  u16x4 o;
  #pragma unroll
  for (int j = 0; j < 4; j++) o[j] = f2bf(v[j]);
  *(u16x4*)(out + i) = o;
}

__global__ __launch_bounds__(256) void zero_kernel(unsigned short* __restrict__ out, long n) {
  long i = ((long)blockIdx.x * 256 + threadIdx.x) * 4;
  if (i >= n) return;
  u16x4 z = {0, 0, 0, 0};
  *(u16x4*)(out + i) = z;
}

__device__ inline void storev(unsigned short* p, float v) { *p = f2bf(v); }
__device__ inline void storev(float* p, float v) { *p = v; }

// C[M,N] = A[M,K] (row-major, lda) * B[N,K]^T (row-major, ldb)
// grid: (N/128, M/128), block 256 (4 waves, 2x2 of 64x64).
// m97 staging + 2-phase double-buffer with COUNTED vmcnt(4); min 3 waves/EU
// so 3 blocks/CU co-reside where the grid allows (cross-block latency hiding).
template <typename OutT>
__global__ __launch_bounds__(256, 3) void gemm_bt(
    const unsigned short* __restrict__ A, int lda,
    const unsigned short* __restrict__ B, int ldb,
    OutT* __restrict__ C, int ldc, int K) {
  __shared__ unsigned short lA[2][128 * 32];
  __shared__ unsigned short lB[2][128 * 32];
  const int tid = threadIdx.x;
  const int lane = tid & 63, wave = tid >> 6;
  const int wr = wave >> 1, wc = wave & 1;
  const int l16 = lane & 15, lhi = lane >> 4;
  const long bm = (long)blockIdx.y * 128, bn = (long)blockIdx.x * 128;
  f32x4 acc[4][4];
  #pragma unroll
  for (int m = 0; m < 4; m++)
    #pragma unroll
    for (int n = 0; n < 4; n++) acc[m][n] = (f32x4){0.f, 0.f, 0.f, 0.f};
  const int srow = wave * 16 + (lane >> 2);
  const int scol = (lane & 3) * 8;
  const unsigned short* Ag0 = A + (bm + srow) * lda + scol;
  const unsigned short* Ag1 = A + (bm + 64 + srow) * lda + scol;
  const unsigned short* Bg0 = B + (bn + srow) * ldb + scol;
  const unsigned short* Bg1 = B + (bn + 64 + srow) * ldb + scol;
  auto stage = [&](int buf, int k0) {
    gload16(Ag0 + k0, &lA[buf][wave * 512]);
    gload16(Ag1 + k0, &lA[buf][2048 + wave * 512]);
    gload16(Bg0 + k0, &lB[buf][wave * 512]);
    gload16(Bg1 + k0, &lB[buf][2048 + wave * 512]);
  };
  const int nt = K >> 5;
  stage(0, 0);
  for (int t = 0; t < nt; ++t) {
    const int cur = t & 1;
    if (t + 1 < nt) {
      stage(cur ^ 1, (t + 1) * 32);                  // prefetch flies over compute
      asm volatile("s_waitcnt vmcnt(4)" ::: "memory");  // cur's 4 loads done
    } else {
      asm volatile("s_waitcnt vmcnt(0)" ::: "memory");
    }
    __builtin_amdgcn_s_barrier();                    // cur staged for all waves
    bf16x8 af[4], bfv[4];
    #pragma unroll
    for (int m = 0; m < 4; m++)
      af[m] = *(const bf16x8*)&lA[cur][(wr * 64 + m * 16 + l16) * 32 + lhi * 8];
    #pragma unroll
    for (int n = 0; n < 4; n++)
      bfv[n] = *(const bf16x8*)&lB[cur][(wc * 64 + n * 16 + l16) * 32 + lhi * 8];
    #pragma unroll
    for (int m = 0; m < 4; m++)
      #pragma unroll
      for (int n = 0; n < 4; n++)
        acc[m][n] = __builtin_amdgcn_mfma_f32_16x16x32_bf16(af[m], bfv[n], acc[m][n], 0, 0, 0);
    asm volatile("s_waitcnt lgkmcnt(0)" ::: "memory");  // my reads of cur complete
    __builtin_amdgcn_sched_barrier(0);
    __builtin_amdgcn_s_barrier();                    // cur free to overwrite at t+2
  }
  #pragma unroll
  for (int m = 0; m < 4; m++)
    #pragma unroll
    for (int n = 0; n < 4; n++) {
      long row = bm + wr * 64 + m * 16 + lhi * 4;
      long col = bn + wc * 64 + n * 16 + l16;
      #pragma unroll
      for (int i = 0; i < 4; i++) storev(&C[(row + i) * ldc + col], acc[m][n][i]);
    }
}

// in-place rmsnorm of bf16 rows; one block per row
__global__ __launch_bounds__(256) void rmsnorm_kernel(unsigned short* __restrict__ buf,
                                                      const float* __restrict__ w,
                                                      int width, int lda) {
  const int tid = threadIdx.x;
  unsigned short* p = buf + (long)blockIdx.x * lda;
  float ss = 0.f;
  const int nc = width >> 2;
  for (int c = tid; c < nc; c += 256) {
    u16x4 v = *(const u16x4*)(p + c * 4);
    #pragma unroll
    for (int j = 0; j < 4; j++) { float f = bf2f(v[j]); ss += f * f; }
  }
  #pragma unroll
  for (int off = 32; off; off >>= 1) ss += __shfl_xor(ss, off);
  __shared__ float red[4];
  if ((tid & 63) == 0) red[tid >> 6] = ss;
  __syncthreads();
  float tot = red[0] + red[1] + red[2] + red[3];
  float rn = rsqrtf(tot / (float)width + 1e-6f);
  for (int c = tid; c < nc; c += 256) {
    u16x4 v = *(const u16x4*)(p + c * 4);
    u16x4 o;
    #pragma unroll
    for (int j = 0; j < 4; j++) o[j] = f2bf(bf2f(v[j]) * rn * w[c * 4 + j]);
    *(u16x4*)(p + c * 4) = o;
  }
}

__global__ __launch_bounds__(256) void rope_q_kernel(unsigned short* __restrict__ q,
                                                     const float* __restrict__ fr) {
  int idx = blockIdx.x * 256 + threadIdx.x;  // (tok, h, pair)
  int pair = idx & 31, h = (idx >> 5) & 15, tok = idx >> 9;
  int s = tok & (SEQ - 1);
  unsigned short* p = q + (long)tok * QDIM + h * QKH + NOPE_D + pair * 2;
  float c = fr[(s * 32 + pair) * 2 + 0], sn = fr[(s * 32 + pair) * 2 + 1];
  float xr = bf2f(p[0]), xi = bf2f(p[1]);
  p[0] = f2bf(xr * c - xi * sn);
  p[1] = f2bf(xr * sn + xi * c);
}

// cb points at the kv-latent sub-buffer (row stride CSTR)
__global__ __launch_bounds__(256) void rope_k_kernel(unsigned short* __restrict__ cb,
                                                     const float* __restrict__ fr) {
  int idx = blockIdx.x * 256 + threadIdx.x;  // (tok, pair)
  int pair = idx & 31, tok = idx >> 5;
  int s = tok & (SEQ - 1);
  unsigned short* p = cb + (long)tok * CSTR + KVR + pair * 2;
  float c = fr[(s * 32 + pair) * 2 + 0], sn = fr[(s * 32 + pair) * 2 + 1];
  float xr = bf2f(p[0]), xi = bf2f(p[1]);
  p[0] = f2bf(xr * c - xi * sn);
  p[1] = f2bf(xr * sn + xi * c);
}

// Flash-style causal attention. 256 blocks (8 pair x 16 h x 2 b), 512 thr
// (8 waves x 16 q-rows, QBLK=128). Two complementary q-tiles per block (uniform
// 36 tile-works). lK/lV XOR-swizzled; T14 reg-prefetch; diagonal-only masking.
// NEW: ones-column in lV -> PV's 9th n-frag accumulates the softmax denominator
// in oacc[8] (no shuffle sum-reduce, no lr bookkeeping). T13 defer-max: skip
// max-reduce + rescale when the tile max is within 8 of the running max.
__global__ __launch_bounds__(512, 2) void attn_kernel(
    const unsigned short* __restrict__ qb,
    const unsigned short* __restrict__ kvb,
    const unsigned short* __restrict__ cb,
    unsigned short* __restrict__ ao) {
  const int bi = blockIdx.x;
  const int pr = bi & 7, h = (bi >> 3) & 15, b = bi >> 7;
  const int tid = threadIdx.x, wave = tid >> 6, lane = tid & 63;
  const int l16 = lane & 15, lhi = lane >> 4;
  const long tbase = (long)b * SEQ;
  __shared__ unsigned short lK[64][192];   // [key][d], col^=(row&7)*8 swizzle
  __shared__ unsigned short lV[144][64];   // [d][key] transposed, swizzled; rows 128..143 = 1.0
  __shared__ unsigned short lP[8][16][72]; // per-wave P tile
  const float scale = 0.0721687836f;  // 1/sqrt(192)
  const int sw = l16 & 7;             // read-side swizzle key
  // prefetch registers
  u16x8 kreg[3];
  u16x8 vreg[2];
  const int vpr = tid & 31, vd0 = (tid >> 5) * 8;

  // fill ones rows once (never overwritten afterwards)
  if (tid < 128) {
    u16x8 ones;
    #pragma unroll
    for (int j = 0; j < 8; j++) ones[j] = 0x3F80;
    *(u16x8*)&lV[128 + (tid >> 3)][(tid & 7) * 8] = ones;
  }

  auto load_tile = [&](int k0) {
    #pragma unroll
    for (int it = 0; it < 3; it++) {
      int c = tid + it * 512;
      int row = c / 24, ch = c % 24;
      const unsigned short* src = (ch < 16)
          ? kvb + (tbase + k0 + row) * KVDIM + h * 256 + ch * 8
          : cb + (tbase + k0 + row) * CSTR + KVR + (ch - 16) * 8;
      kreg[it] = *(const u16x8*)src;
    }
    const unsigned short* v0 = kvb + (tbase + k0 + 2 * vpr) * KVDIM + h * 256 + 128 + vd0;
    vreg[0] = *(const u16x8*)v0;
    vreg[1] = *(const u16x8*)(v0 + KVDIM);
  };
  auto write_tile = [&]() {
    #pragma unroll
    for (int it = 0; it < 3; it++) {
      int c = tid + it * 512;
      int row = c / 24, ch = c % 24;
      *(u16x8*)&lK[row][(ch ^ (row & 7)) * 8] = kreg[it];
    }
    #pragma unroll
    for (int j = 0; j < 8; j++)
      *(uint32_t*)&lV[vd0 + j][(2 * vpr) ^ (j << 3)] =
          (uint32_t)vreg[0][j] | ((uint32_t)vreg[1][j] << 16);
  };

  for (int sub = 0; sub < 2; sub++) {
    const int qt = sub ? (15 - pr) : pr;
    const int q0 = qt * 128;
    bf16x8 qf[6];
    {
      const unsigned short* qg = qb + (tbase + q0 + wave * 16 + l16) * QDIM + h * QKH;
      #pragma unroll
      for (int d = 0; d < 6; d++) qf[d] = *(const bf16x8*)(qg + d * 32 + lhi * 8);
    }
    f32x4 oacc[9];   // [0..7] = O cols, [8] = softmax denominator (ones-column)
    #pragma unroll
    for (int n = 0; n < 9; n++) oacc[n] = (f32x4){0.f, 0.f, 0.f, 0.f};
    float mr[4];
    #pragma unroll
    for (int i = 0; i < 4; i++) mr[i] = -1e30f;
    const int qrow = q0 + wave * 16 + lhi * 4;

    const int nkt = 2 * qt + 2;
    load_tile(0);
    for (int kt = 0; kt < nkt; kt++) {
      const int k0 = kt * 64;
      __syncthreads();          // all waves done reading previous tile's LDS
      write_tile();
      __syncthreads();          // staged tile visible
      if (kt + 1 < nkt) load_tile((kt + 1) * 64);  // flies during compute
      // QK^T: wave's 16 q-rows x 64 keys
      f32x4 sc[4];
      #pragma unroll
      for (int ks = 0; ks < 4; ks++) {
        sc[ks] = (f32x4){0.f, 0.f, 0.f, 0.f};
        #pragma unroll
        for (int d = 0; d < 6; d++) {
          bf16x8 kf = *(const bf16x8*)&lK[ks * 16 + l16][((4 * d + lhi) ^ sw) * 8];
          sc[ks] = __builtin_amdgcn_mfma_f32_16x16x32_bf16(qf[d], kf, sc[ks], 0, 0, 0);
        }
      }
      // scale always; causal mask only when the tile can touch the diagonal
      #pragma unroll
      for (int ks = 0; ks < 4; ks++)
        #pragma unroll
        for (int i = 0; i < 4; i++) sc[ks][i] *= scale;
      if (kt >= 2 * qt) {
        #pragma unroll
        for (int ks = 0; ks < 4; ks++) {
          const int kcol = k0 + ks * 16 + l16;
          #pragma unroll
          for (int i = 0; i < 4; i++)
            if (kcol > qrow + i) sc[ks][i] = -1e30f;
        }
      }
      // T13 defer-max: only reduce max + rescale when a lane's tile max grew past mr+8
      float pmax[4];
      #pragma unroll
      for (int i = 0; i < 4; i++)
        pmax[i] = fmaxf(fmaxf(sc[0][i], sc[1][i]), fmaxf(sc[2][i], sc[3][i]));
      bool ok = (pmax[0] <= mr[0] + 8.f) && (pmax[1] <= mr[1] + 8.f) &&
                (pmax[2] <= mr[2] + 8.f) && (pmax[3] <= mr[3] + 8.f);
      if (!__all(ok)) {
        float fac[4];
        #pragma unroll
        for (int i = 0; i < 4; i++) {
          float mx = pmax[i];
          #pragma unroll
          for (int off = 1; off < 16; off <<= 1) mx = fmaxf(mx, __shfl_xor(mx, off));
          float mn = fmaxf(mr[i], mx);
          fac[i] = exp2f((mr[i] - mn) * 1.44269504f);
          mr[i] = mn;
        }
        #pragma unroll
        for (int n = 0; n < 9; n++) {
          f32x4 t = oacc[n];
          t[0] *= fac[0]; t[1] *= fac[1]; t[2] *= fac[2]; t[3] *= fac[3];
          oacc[n] = t;
        }
      }
      #pragma unroll
      for (int ks = 0; ks < 4; ks++)
        #pragma unroll
        for (int i = 0; i < 4; i++) {
          float pv = exp2f((sc[ks][i] - mr[i]) * 1.44269504f);
          lP[wave][lhi * 4 + i][ks * 16 + l16] = f2bf(pv);
        }
      // PV: O += P(16x64) * V(64x128), plus ones-column denom in frag 8
      #pragma unroll
      for (int kk = 0; kk < 2; kk++) {
        bf16x8 pf = *(const bf16x8*)&lP[wave][l16][kk * 32 + lhi * 8];
        #pragma unroll
        for (int n = 0; n < 9; n++) {
          bf16x8 vf = *(const bf16x8*)&lV[n * 16 + l16][((kk * 4 + lhi) ^ sw) * 8];
          oacc[n] = __builtin_amdgcn_mfma_f32_16x16x32_bf16(pf, vf, oacc[n], 0, 0, 0);
        }
      }
    }
    #pragma unroll
    for (int n = 0; n < 8; n++)
      #pragma unroll
      for (int i = 0; i < 4; i++) {
        long row = tbase + q0 + wave * 16 + lhi * 4 + i;
        ao[row * ODIM + h * 128 + n * 16 + l16] = f2bf(oacc[n][i] / oacc[8][i]);
      }
  }
}

extern "C" void kernel_launch(void* const* d_in, const int* in_sizes, int n_in,
                              void* d_out, int out_size, void* d_ws, size_t ws_size,
                              hipStream_t stream) {
  const float* x = (const float*)d_in[0];
  const float* fr = (const float*)d_in[1];
  const float* wq_a = (const float*)d_in[2];
  const float* qnw = (const float*)d_in[3];
  const float* wq_b = (const float*)d_in[4];
  const float* wkv_a = (const float*)d_in[5];
  const float* kvnw = (const float*)d_in[6];
  const float* wkv_b = (const float*)d_in[7];
  const float* wo = (const float*)d_in[8];
  float* out = (float*)d_out;

  char* ws = (char*)d_ws;
  size_t o = 0;
  unsigned short* xb = (unsigned short*)(ws + o);    o += (size_t)TOK * NDIM * 2;
  unsigned short* wcomb = (unsigned short*)(ws + o); o += (size_t)CSTR * NDIM * 2;
  unsigned short* wqbb = (unsigned short*)(ws + o);  o += (size_t)QDIM * QR * 2;
  unsigned short* wkvbb = (unsigned short*)(ws + o); o += (size_t)KVDIM * KVR * 2;
  unsigned short* wob = (unsigned short*)(ws + o);   o += (size_t)NDIM * ODIM * 2;
  unsigned short* cw = (unsigned short*)(ws + o);    o += (size_t)TOK * CSTR * 2;
  unsigned short* qbuf = (unsigned short*)(ws + o);  o += (size_t)TOK * QDIM * 2;
  unsigned short* kvbuf = (unsigned short*)(ws + o); o += (size_t)TOK * KVDIM * 2;
  unsigned short* aout = (unsigned short*)(ws + o);  o += (size_t)TOK * ODIM * 2;
  unsigned short* ckv = cw + QR;  // kv-latent+rope sub-buffer, row stride CSTR

  cvt_kernel<<<(TOK * (long)NDIM) / 1024, 256, 0, stream>>>(x, xb, (long)TOK * NDIM);
  cvt_kernel<<<((long)QR * NDIM) / 1024, 256, 0, stream>>>(wq_a, wcomb, (long)QR * NDIM);
  cvt_kernel<<<((long)576 * NDIM) / 1024, 256, 0, stream>>>(
      wkv_a, wcomb + (size_t)QR * NDIM, (long)576 * NDIM);
  zero_kernel<<<((long)64 * NDIM) / 1024, 256, 0, stream>>>(
      wcomb + (size_t)(QR + 576) * NDIM, (long)64 * NDIM);
  cvt_kernel<<<((long)QDIM * QR) / 1024, 256, 0, stream>>>(wq_b, wqbb, (long)QDIM * QR);
  cvt_kernel<<<((long)KVDIM * KVR) / 1024, 256, 0, stream>>>(wkv_b, wkvbb, (long)KVDIM * KVR);
  cvt_kernel<<<((long)NDIM * ODIM) / 1024, 256, 0, stream>>>(wo, wob, (long)NDIM * ODIM);

  dim3 blk(256);
  // merged q-latent + kv-latent projection: N = 2176
  gemm_bt<unsigned short><<<dim3(CSTR / 128, TOK / 128), blk, 0, stream>>>(
      xb, NDIM, wcomb, NDIM, cw, CSTR, NDIM);
  rmsnorm_kernel<<<TOK, 256, 0, stream>>>(cw, qnw, QR, CSTR);
  rmsnorm_kernel<<<TOK, 256, 0, stream>>>(ckv, kvnw, KVR, CSTR);
  gemm_bt<unsigned short><<<dim3(QDIM / 128, TOK / 128), blk, 0, stream>>>(
      cw, CSTR, wqbb, QR, qbuf, QDIM, QR);
  gemm_bt<unsigned short><<<dim3(KVDIM / 128, TOK / 128), blk, 0, stream>>>(
      ckv, CSTR, wkvbb, KVR, kvbuf, KVDIM, KVR);
  rope_q_kernel<<<(TOK * NH * 32) / 256, 256, 0, stream>>>(qbuf, fr);
  rope_k_kernel<<<(TOK * 32) / 256, 256, 0, stream>>>(ckv, fr);
  attn_kernel<<<dim3(256, 1, 1), 512, 0, stream>>>(qbuf, kvbuf, ckv, aout);
  gemm_bt<float><<<dim3(ODIM / 128, TOK / 128), blk, 0, stream>>>(
      aout, ODIM, wob, ODIM, out, ODIM, ODIM);
}